// Round 1
// baseline (862.983 us; speedup 1.0000x reference)
//
#include <hip/hip_runtime.h>
#include <cstdint>

// ---------------------------------------------------------------------------
// GCN graph classification on MI355X.
// Pipeline (algebraically reordered so SpMM runs on the *narrow* features):
//   deg -> cj=rsqrt(outdeg), ci=rsqrt(indeg)
//   a1[n] = sum_{e: dst=n} cj[src] * x[src]            (SpMM gather, F=128)
//   h1    = relu((a1 @ W1) * ci + b1)                  (GEMM, fused epilogue)
//   a2[n] = sum_{e: dst=n} cj[src] * h1[src]           (SpMM gather, F=256)
//   gsum[g] += (a2 @ W2) * ci + b2    per node row     (GEMM, atomic epilogue)
//   out = (gsum/cnt) @ Wl + bl                         (tiny GEMM)
// ---------------------------------------------------------------------------

__global__ void k_degrees(const int* __restrict__ src, const int* __restrict__ dst,
                          int* __restrict__ outdeg, int* __restrict__ indeg, int E) {
  int i = blockIdx.x * blockDim.x + threadIdx.x;
  if (i < E) {
    atomicAdd(&outdeg[src[i]], 1);
    atomicAdd(&indeg[dst[i]], 1);
  }
}

// cj/ci norms + CSR row allocation (wave-aggregated atomic bump allocator).
__global__ void k_norms_rows(const int* __restrict__ outdeg, const int* __restrict__ indeg,
                             float* __restrict__ cj, float* __restrict__ ci,
                             int* __restrict__ row_start, int* __restrict__ counter, int N) {
  int i = blockIdx.x * blockDim.x + threadIdx.x;
  int din = 0;
  if (i < N) {
    int dout = outdeg[i];
    din = indeg[i];
    cj[i] = rsqrtf((float)(dout > 1 ? dout : 1));
    ci[i] = rsqrtf((float)(din  > 1 ? din  : 1));
  }
  int lane = threadIdx.x & 63;
  int inc = din;
#pragma unroll
  for (int off = 1; off < 64; off <<= 1) {
    int o = __shfl_up(inc, off);
    if (lane >= off) inc += o;
  }
  int excl = inc - din;
  int wsum = __shfl(inc, 63);
  int base = 0;
  if (lane == 0) base = atomicAdd(counter, wsum);
  base = __shfl(base, 0);
  if (i < N) row_start[i] = base + excl;
}

__global__ void k_fill(const int* __restrict__ src, const int* __restrict__ dst,
                       const int* __restrict__ row_start, int* __restrict__ cursor,
                       int* __restrict__ csr_src, int E) {
  int i = blockIdx.x * blockDim.x + threadIdx.x;
  if (i < E) {
    int d = dst[i];
    int pos = row_start[d] + atomicAdd(&cursor[d], 1);
    csr_src[pos] = src[i];
  }
}

// One 64-thread block per destination node; gathers cj[s]*feat[s,:] rows.
template <int F>  // 128 (V=2) or 256 (V=4)
__global__ void k_spmm(const float* __restrict__ feat, const float* __restrict__ cj,
                       const int* __restrict__ row_start, const int* __restrict__ cnts,
                       const int* __restrict__ csr_src, float* __restrict__ out, int N) {
  int n = blockIdx.x;
  if (n >= N) return;
  int beg = row_start[n];
  int cnt = cnts[n];
  constexpr int V = F / 64;
  int t = threadIdx.x;
  float acc[V];
#pragma unroll
  for (int v = 0; v < V; ++v) acc[v] = 0.f;
  for (int k = 0; k < cnt; ++k) {
    int s = csr_src[beg + k];
    float c = cj[s];
    const float* p = feat + (size_t)s * F + t * V;
    if constexpr (V == 4) {
      float4 v = *(const float4*)p;
      acc[0] += c * v.x; acc[1] += c * v.y; acc[2] += c * v.z; acc[3] += c * v.w;
    } else {
      float2 v = *(const float2*)p;
      acc[0] += c * v.x; acc[1] += c * v.y;
    }
  }
  float* o = out + (size_t)n * F + t * V;
  if constexpr (V == 4) {
    float4 v; v.x = acc[0]; v.y = acc[1]; v.z = acc[2]; v.w = acc[3];
    *(float4*)o = v;
  } else {
    float2 v; v.x = acc[0]; v.y = acc[1];
    *(float2*)o = v;
  }
}

// f32 GEMM: C[M,256] = A[M,K] @ B[K,256], 64x64 tile, 4x4 per thread.
// EPI 0: out = relu(acc*ci[row] + bias[col])   (writes out[M,256])
// EPI 1: atomicAdd(gsum[gid[row]*256+col], acc*ci[row] + bias[col])
template <int K, int EPI>
__global__ __launch_bounds__(256)
void k_gemm(const float* __restrict__ A, const float* __restrict__ B,
            const float* __restrict__ ci, const float* __restrict__ bias,
            const int* __restrict__ gids, float* __restrict__ out, int M) {
  constexpr int KT = 32;
  __shared__ float As[KT][68];  // transposed: As[k][r]
  __shared__ float Bs[KT][68];
  const int tid = threadIdx.x;
  const int tx = tid & 15, ty = tid >> 4;
  const int row0 = blockIdx.x * 64;
  const int col0 = blockIdx.y * 64;
  float acc[4][4] = {};
  for (int k0 = 0; k0 < K; k0 += KT) {
    {
      int kq = tid & 7;   // k quad (4 floats)
      int r  = tid >> 3;  // 0..31
#pragma unroll
      for (int h = 0; h < 2; ++h) {
        int rr = r + h * 32;
        int grow = row0 + rr; if (grow > M - 1) grow = M - 1;
        const float4 v = *(const float4*)(A + (size_t)grow * K + k0 + kq * 4);
        As[kq * 4 + 0][rr] = v.x;
        As[kq * 4 + 1][rr] = v.y;
        As[kq * 4 + 2][rr] = v.z;
        As[kq * 4 + 3][rr] = v.w;
      }
    }
    {
      int c4 = tid & 15;  // col quad
      int kk = tid >> 4;  // 0..15
#pragma unroll
      for (int h = 0; h < 2; ++h) {
        int kkk = kk + h * 16;
        const float4 v = *(const float4*)(B + (size_t)(k0 + kkk) * 256 + col0 + c4 * 4);
        *(float4*)&Bs[kkk][c4 * 4] = v;
      }
    }
    __syncthreads();
#pragma unroll
    for (int kk = 0; kk < KT; ++kk) {
      float4 a = *(const float4*)&As[kk][ty * 4];
      float4 b = *(const float4*)&Bs[kk][tx * 4];
      float av[4] = {a.x, a.y, a.z, a.w};
      float bv[4] = {b.x, b.y, b.z, b.w};
#pragma unroll
      for (int i = 0; i < 4; ++i)
#pragma unroll
        for (int j = 0; j < 4; ++j) acc[i][j] += av[i] * bv[j];
    }
    __syncthreads();
  }
#pragma unroll
  for (int i = 0; i < 4; ++i) {
    int row = row0 + ty * 4 + i;
    if (row < M) {
      float cir = ci[row];
      int colb = col0 + tx * 4;
      if constexpr (EPI == 0) {
        float4 v;
        v.x = fmaxf(acc[i][0] * cir + bias[colb + 0], 0.f);
        v.y = fmaxf(acc[i][1] * cir + bias[colb + 1], 0.f);
        v.z = fmaxf(acc[i][2] * cir + bias[colb + 2], 0.f);
        v.w = fmaxf(acc[i][3] * cir + bias[colb + 3], 0.f);
        *(float4*)(out + (size_t)row * 256 + colb) = v;
      } else {
        int g = gids[row];
        float* dp = out + (size_t)g * 256 + colb;
        atomicAdd(dp + 0, acc[i][0] * cir + bias[colb + 0]);
        atomicAdd(dp + 1, acc[i][1] * cir + bias[colb + 1]);
        atomicAdd(dp + 2, acc[i][2] * cir + bias[colb + 2]);
        atomicAdd(dp + 3, acc[i][3] * cir + bias[colb + 3]);
      }
    }
  }
}

// out[g,l] = (gsum[g,:]/cnt_g) @ Wl[:,l] + bl[l]; cnt via binary search (sorted ids).
__global__ void k_readout(const float* __restrict__ gsum, const int* __restrict__ gids,
                          const float* __restrict__ Wl, const float* __restrict__ bl,
                          float* __restrict__ out, int N, int da, int L) {
  int g = blockIdx.x;
  int lo = 0, hi = N;
  while (lo < hi) { int m = (lo + hi) >> 1; if (gids[m] < g) lo = m + 1; else hi = m; }
  int lo2 = lo, hi2 = N;
  while (lo2 < hi2) { int m = (lo2 + hi2) >> 1; if (gids[m] < g + 1) lo2 = m + 1; else hi2 = m; }
  int cnt = lo2 - lo;
  float inv = 1.0f / (float)(cnt > 1 ? cnt : 1);
  int l = threadIdx.x;
  if (l < L) {
    float acc = bl[l];
    for (int k = 0; k < da; ++k) acc += gsum[g * da + k] * inv * Wl[k * L + l];
    out[g * L + l] = acc;
  }
}

extern "C" void kernel_launch(void* const* d_in, const int* in_sizes, int n_in,
                              void* d_out, int out_size, void* d_ws, size_t ws_size,
                              hipStream_t stream) {
  const float* x   = (const float*)d_in[0];
  const int*   src = (const int*)d_in[1];
  const int*   dst = (const int*)d_in[2];
  const int*   gid = (const int*)d_in[3];
  const float* W1  = (const float*)d_in[5];
  const float* b1  = (const float*)d_in[6];
  const float* W2  = (const float*)d_in[7];
  const float* b2  = (const float*)d_in[8];
  const float* Wl  = (const float*)d_in[9];
  const float* bl  = (const float*)d_in[10];
  float* out = (float*)d_out;

  const int N  = in_sizes[3];       // 50000
  const int E  = in_sizes[1];       // 800000
  const int da = in_sizes[8];       // 256 (W2 is [u,da] flattened; u==256 too)
  const int L  = in_sizes[10];      // 50
  const int G  = out_size / L;      // 64

  char* p = (char*)d_ws;
  int*   outdeg   = (int*)p;   p += (size_t)N * 4;
  int*   indeg    = (int*)p;   p += (size_t)N * 4;
  int*   cursor   = (int*)p;   p += (size_t)N * 4;
  int*   counter  = (int*)p;   p += 256;
  float* gsum     = (float*)p; p += (size_t)G * 256 * 4;
  size_t zero_bytes = (size_t)(p - (char*)d_ws);
  float* cj       = (float*)p; p += (size_t)N * 4;
  float* ci       = (float*)p; p += (size_t)N * 4;
  int*   row_start= (int*)p;   p += (size_t)N * 4;
  int*   csr_src  = (int*)p;   p += (size_t)E * 4;
  float* bufA     = (float*)p; p += (size_t)N * 256 * 4;  // a1 (128 cols) then a2 (256)
  float* bufB     = (float*)p; p += (size_t)N * 256 * 4;  // h1
  (void)ws_size; (void)n_in;

  hipMemsetAsync(d_ws, 0, zero_bytes, stream);
  k_degrees<<<(E + 255) / 256, 256, 0, stream>>>(src, dst, outdeg, indeg, E);
  k_norms_rows<<<(N + 255) / 256, 256, 0, stream>>>(outdeg, indeg, cj, ci, row_start, counter, N);
  k_fill<<<(E + 255) / 256, 256, 0, stream>>>(src, dst, row_start, cursor, csr_src, E);

  k_spmm<128><<<N, 64, 0, stream>>>(x, cj, row_start, indeg, csr_src, bufA, N);

  dim3 gg((N + 63) / 64, 4);
  k_gemm<128, 0><<<gg, 256, 0, stream>>>(bufA, W1, ci, b1, nullptr, bufB, N);

  k_spmm<256><<<N, 64, 0, stream>>>(bufB, cj, row_start, indeg, csr_src, bufA, N);

  k_gemm<256, 1><<<gg, 256, 0, stream>>>(bufA, W2, ci, b2, gid, gsum, N);

  k_readout<<<G, 64, 0, stream>>>(gsum, gid, Wl, bl, out, N, da, L);
}

// Round 2
// 495.469 us; speedup vs baseline: 1.7418x; 1.7418x over previous
//
#include <hip/hip_runtime.h>
#include <cstdint>

// ---------------------------------------------------------------------------
// GCN graph classification on MI355X (gfx950), bf16 MFMA edition.
//   deg -> cj=rsqrt(outdeg), ci=rsqrt(indeg); CSR by dst built on device
//   xb  = bf16(x)
//   a1[n] = sum_{e: dst=n} cj[src] * xb[src]          (SpMM gather, F=128, bf16)
//   h1    = relu((a1 @ W1) * ci + b1)                 (MFMA GEMM, bf16 out)
//   a2[n] = sum_{e: dst=n} cj[src] * h1[src]          (SpMM gather, F=256, bf16)
//   gsum[g] += (a2 @ W2) * ci + b2   per node row     (MFMA GEMM, atomic epi)
//   out = (gsum/cnt) @ Wl + bl                        (tiny GEMM)
// ---------------------------------------------------------------------------

typedef __attribute__((ext_vector_type(8))) short short8v;
typedef __attribute__((ext_vector_type(4))) float f32x4;

static __device__ __forceinline__ unsigned short f2bf(float f) {
  unsigned u = __float_as_uint(f);
  u += 0x7FFFu + ((u >> 16) & 1u);   // RTNE
  return (unsigned short)(u >> 16);
}
static __device__ __forceinline__ float bf2f(unsigned short h) {
  return __uint_as_float(((unsigned)h) << 16);
}

__global__ void k_degrees(const int* __restrict__ src, const int* __restrict__ dst,
                          int* __restrict__ outdeg, int* __restrict__ indeg, int E) {
  int i = blockIdx.x * blockDim.x + threadIdx.x;
  if (i < E) {
    atomicAdd(&outdeg[src[i]], 1);
    atomicAdd(&indeg[dst[i]], 1);
  }
}

__global__ void k_norms_rows(const int* __restrict__ outdeg, const int* __restrict__ indeg,
                             float* __restrict__ cj, float* __restrict__ ci,
                             int* __restrict__ row_start, int* __restrict__ counter, int N) {
  int i = blockIdx.x * blockDim.x + threadIdx.x;
  int din = 0;
  if (i < N) {
    int dout = outdeg[i];
    din = indeg[i];
    cj[i] = rsqrtf((float)(dout > 1 ? dout : 1));
    ci[i] = rsqrtf((float)(din  > 1 ? din  : 1));
  }
  int lane = threadIdx.x & 63;
  int inc = din;
#pragma unroll
  for (int off = 1; off < 64; off <<= 1) {
    int o = __shfl_up(inc, off);
    if (lane >= off) inc += o;
  }
  int excl = inc - din;
  int wsum = __shfl(inc, 63);
  int base = 0;
  if (lane == 0) base = atomicAdd(counter, wsum);
  base = __shfl(base, 0);
  if (i < N) row_start[i] = base + excl;
}

__global__ void k_fill(const int* __restrict__ src, const int* __restrict__ dst,
                       const int* __restrict__ row_start, int* __restrict__ cursor,
                       int* __restrict__ csr_src, int E) {
  int i = blockIdx.x * blockDim.x + threadIdx.x;
  if (i < E) {
    int d = dst[i];
    int pos = row_start[d] + atomicAdd(&cursor[d], 1);
    csr_src[pos] = src[i];
  }
}

// f32 -> bf16 cast, 4 elements/thread.
__global__ void k_cast4(const float4* __restrict__ x, unsigned short* __restrict__ o, int n4) {
  int i = blockIdx.x * blockDim.x + threadIdx.x;
  if (i < n4) {
    float4 v = x[i];
    uint2 r;
    r.x = (unsigned)f2bf(v.x) | ((unsigned)f2bf(v.y) << 16);
    r.y = (unsigned)f2bf(v.z) | ((unsigned)f2bf(v.w) << 16);
    *(uint2*)(o + (size_t)i * 4) = r;
  }
}

// W[K][Nn] f32 -> BT[Nn][K] bf16 (transpose + cast; tiny).
__global__ void k_castT(const float* __restrict__ W, unsigned short* __restrict__ BT,
                        int K, int Nn) {
  int i = blockIdx.x * blockDim.x + threadIdx.x;
  if (i < K * Nn) {
    int k = i / Nn, nn = i - k * Nn;
    BT[(size_t)nn * K + k] = f2bf(W[i]);
  }
}

// One 64-thread block per destination node; bf16 rows, f32 accumulate.
// VU = uints per lane per row (1 -> F=128, 2 -> F=256).
template <int VU>
__global__ void k_spmm(const unsigned* __restrict__ feat, const float* __restrict__ cj,
                       const int* __restrict__ row_start, const int* __restrict__ cnts,
                       const int* __restrict__ csr_src, unsigned* __restrict__ out, int N) {
  int n = blockIdx.x;
  if (n >= N) return;
  int beg = row_start[n];
  int cnt = cnts[n];
  int t = threadIdx.x;
  const int stride = VU * 64;
  float acc[2 * VU];
#pragma unroll
  for (int v = 0; v < 2 * VU; ++v) acc[v] = 0.f;
  for (int k = 0; k < cnt; ++k) {
    int s = csr_src[beg + k];
    float c = cj[s];
    const unsigned* p = feat + (size_t)s * stride + t * VU;
    if constexpr (VU == 2) {
      uint2 w = *(const uint2*)p;
      acc[0] += c * bf2f((unsigned short)(w.x & 0xFFFF));
      acc[1] += c * bf2f((unsigned short)(w.x >> 16));
      acc[2] += c * bf2f((unsigned short)(w.y & 0xFFFF));
      acc[3] += c * bf2f((unsigned short)(w.y >> 16));
    } else {
      unsigned w = *p;
      acc[0] += c * bf2f((unsigned short)(w & 0xFFFF));
      acc[1] += c * bf2f((unsigned short)(w >> 16));
    }
  }
  unsigned* o = out + (size_t)n * stride + t * VU;
  if constexpr (VU == 2) {
    uint2 r;
    r.x = (unsigned)f2bf(acc[0]) | ((unsigned)f2bf(acc[1]) << 16);
    r.y = (unsigned)f2bf(acc[2]) | ((unsigned)f2bf(acc[3]) << 16);
    *(uint2*)o = r;
  } else {
    *o = (unsigned)f2bf(acc[0]) | ((unsigned)f2bf(acc[1]) << 16);
  }
}

// MFMA GEMM: C[M,256] = A[M,K](bf16) @ B[K,256](bf16, given as BT[256][K]).
// Block: 256 thr = 4 waves; block tile 64 rows x 64 cols; wave = 16 rows.
// EPI 0: h1[row,col] = bf16(relu(acc*ci[row] + bias[col]))
// EPI 1: atomicAdd(gsum[gid[row]*256+col], acc*ci[row] + bias[col])
template <int K, int EPI>
__global__ __launch_bounds__(256)
void k_gemm_mfma(const unsigned short* __restrict__ A, const unsigned short* __restrict__ BT,
                 const float* __restrict__ ci, const float* __restrict__ bias,
                 const int* __restrict__ gids, void* __restrict__ outp, int M) {
  const int lane = threadIdx.x & 63;
  const int wave = threadIdx.x >> 6;
  const int row0 = blockIdx.x * 64 + wave * 16;
  const int col0 = blockIdx.y * 64;
  const int l15 = lane & 15;
  const int kA = (lane >> 4) * 8;

  f32x4 acc[4];
#pragma unroll
  for (int i = 0; i < 4; ++i) acc[i] = (f32x4){0.f, 0.f, 0.f, 0.f};

  const unsigned short* aRow = A + (size_t)(row0 + l15) * K + kA;
#pragma unroll
  for (int kc = 0; kc < K; kc += 32) {
    short8v av = *(const short8v*)(aRow + kc);
#pragma unroll
    for (int ct = 0; ct < 4; ++ct) {
      int cB = col0 + ct * 16 + l15;
      short8v bv = *(const short8v*)(BT + (size_t)cB * K + kc + kA);
      acc[ct] = __builtin_amdgcn_mfma_f32_16x16x32_bf16(av, bv, acc[ct], 0, 0, 0);
    }
  }

  const int rBase = row0 + (lane >> 4) * 4;
  if constexpr (EPI == 0) {
    unsigned short* out = (unsigned short*)outp;
#pragma unroll
    for (int r = 0; r < 4; ++r) {
      int row = rBase + r;
      if (row < M) {
        float cir = ci[row];
#pragma unroll
        for (int ct = 0; ct < 4; ++ct) {
          int col = col0 + ct * 16 + l15;
          float v = acc[ct][r] * cir + bias[col];
          out[(size_t)row * 256 + col] = f2bf(fmaxf(v, 0.f));
        }
      }
    }
  } else {
    float* gsum = (float*)outp;
    int g[4];
    float cir[4];
#pragma unroll
    for (int r = 0; r < 4; ++r) {
      int row = rBase + r;
      bool ok = row < M;
      g[r] = ok ? gids[row] : -1;
      cir[r] = ok ? ci[row] : 0.f;
    }
#pragma unroll
    for (int ct = 0; ct < 4; ++ct) {
      int col = col0 + ct * 16 + l15;
      float bb = bias[col];
      float v0 = acc[ct][0] * cir[0] + bb;
      float v1 = acc[ct][1] * cir[1] + bb;
      float v2 = acc[ct][2] * cir[2] + bb;
      float v3 = acc[ct][3] * cir[3] + bb;
      if (g[0] == g[3] && g[0] >= 0) {   // gid sorted -> all 4 equal
        atomicAdd(&gsum[(size_t)g[0] * 256 + col], v0 + v1 + v2 + v3);
      } else {
        if (g[0] >= 0) atomicAdd(&gsum[(size_t)g[0] * 256 + col], v0);
        if (g[1] >= 0) atomicAdd(&gsum[(size_t)g[1] * 256 + col], v1);
        if (g[2] >= 0) atomicAdd(&gsum[(size_t)g[2] * 256 + col], v2);
        if (g[3] >= 0) atomicAdd(&gsum[(size_t)g[3] * 256 + col], v3);
      }
    }
  }
}

__global__ void k_readout(const float* __restrict__ gsum, const int* __restrict__ gids,
                          const float* __restrict__ Wl, const float* __restrict__ bl,
                          float* __restrict__ out, int N, int da, int L) {
  int g = blockIdx.x;
  int lo = 0, hi = N;
  while (lo < hi) { int m = (lo + hi) >> 1; if (gids[m] < g) lo = m + 1; else hi = m; }
  int lo2 = lo, hi2 = N;
  while (lo2 < hi2) { int m = (lo2 + hi2) >> 1; if (gids[m] < g + 1) lo2 = m + 1; else hi2 = m; }
  int cnt = lo2 - lo;
  float inv = 1.0f / (float)(cnt > 1 ? cnt : 1);
  int l = threadIdx.x;
  if (l < L) {
    float acc = bl[l];
    for (int k = 0; k < da; ++k) acc += gsum[g * da + k] * inv * Wl[k * L + l];
    out[g * L + l] = acc;
  }
}

static inline size_t alignup(size_t v) { return (v + 255) & ~(size_t)255; }

extern "C" void kernel_launch(void* const* d_in, const int* in_sizes, int n_in,
                              void* d_out, int out_size, void* d_ws, size_t ws_size,
                              hipStream_t stream) {
  const float* x   = (const float*)d_in[0];
  const int*   src = (const int*)d_in[1];
  const int*   dst = (const int*)d_in[2];
  const int*   gid = (const int*)d_in[3];
  const float* W1  = (const float*)d_in[5];
  const float* b1  = (const float*)d_in[6];
  const float* W2  = (const float*)d_in[7];
  const float* b2  = (const float*)d_in[8];
  const float* Wl  = (const float*)d_in[9];
  const float* bl  = (const float*)d_in[10];
  float* out = (float*)d_out;

  const int N  = in_sizes[3];        // 50000
  const int E  = in_sizes[1];        // 800000
  const int de = in_sizes[0] / N;    // 128
  const int da = in_sizes[8];        // 256
  const int L  = in_sizes[10];       // 50
  const int G  = out_size / L;       // 64
  const int RB = (N + 63) / 64;      // row blocks
  const int Npad = RB * 64;          // padded rows for OOB-safe frag loads

  char* p = (char*)d_ws;
  int*   outdeg   = (int*)p;   p += alignup((size_t)N * 4);
  int*   indeg    = (int*)p;   p += alignup((size_t)N * 4);
  int*   cursor   = (int*)p;   p += alignup((size_t)N * 4);
  int*   counter  = (int*)p;   p += 256;
  float* gsum     = (float*)p; p += alignup((size_t)G * 256 * 4);
  size_t zero_bytes = (size_t)(p - (char*)d_ws);
  float* cj       = (float*)p; p += alignup((size_t)N * 4);
  float* ci       = (float*)p; p += alignup((size_t)N * 4);
  int*   row_start= (int*)p;   p += alignup((size_t)N * 4);
  int*   csr_src  = (int*)p;   p += alignup((size_t)E * 4);
  unsigned short* xb  = (unsigned short*)p; p += alignup((size_t)Npad * 128 * 2);
  unsigned short* a1  = (unsigned short*)p; p += alignup((size_t)Npad * 128 * 2);
  unsigned short* h1  = (unsigned short*)p; p += alignup((size_t)Npad * 256 * 2);
  unsigned short* a2  = (unsigned short*)p; p += alignup((size_t)Npad * 256 * 2);
  unsigned short* BT1 = (unsigned short*)p; p += alignup((size_t)256 * 128 * 2);
  unsigned short* BT2 = (unsigned short*)p; p += alignup((size_t)256 * 256 * 2);
  (void)ws_size; (void)n_in; (void)de;

  hipMemsetAsync(d_ws, 0, zero_bytes, stream);

  k_degrees<<<(E + 255) / 256, 256, 0, stream>>>(src, dst, outdeg, indeg, E);
  k_norms_rows<<<(N + 255) / 256, 256, 0, stream>>>(outdeg, indeg, cj, ci, row_start, counter, N);
  k_fill<<<(E + 255) / 256, 256, 0, stream>>>(src, dst, row_start, cursor, csr_src, E);

  // casts (independent of CSR build)
  k_cast4<<<(N * 128 / 4 + 255) / 256, 256, 0, stream>>>((const float4*)x, xb, N * 128 / 4);
  k_castT<<<(128 * 256 + 255) / 256, 256, 0, stream>>>(W1, BT1, 128, 256);
  k_castT<<<(256 * 256 + 255) / 256, 256, 0, stream>>>(W2, BT2, 256, 256);

  k_spmm<1><<<N, 64, 0, stream>>>((const unsigned*)xb, cj, row_start, indeg, csr_src,
                                  (unsigned*)a1, N);

  dim3 gg(RB, 4);
  k_gemm_mfma<128, 0><<<gg, 256, 0, stream>>>(a1, BT1, ci, b1, nullptr, h1, N);

  k_spmm<2><<<N, 64, 0, stream>>>((const unsigned*)h1, cj, row_start, indeg, csr_src,
                                  (unsigned*)a2, N);

  k_gemm_mfma<256, 1><<<gg, 256, 0, stream>>>(a2, BT2, ci, b2, gid, gsum, N);

  k_readout<<<G, 64, 0, stream>>>(gsum, gid, Wl, bl, out, N, da, L);
}

// Round 3
// 397.133 us; speedup vs baseline: 2.1730x; 1.2476x over previous
//
#include <hip/hip_runtime.h>
#include <cstdint>

// ---------------------------------------------------------------------------
// GCN graph classification on MI355X (gfx950), bf16 MFMA edition, v3.
//   deg -> cj=rsqrt(outdeg), ci=rsqrt(indeg); CSR by dst built on device
//   xb  = bf16(cj * x)                               (cj fused into cast)
//   a1[n] = sum_{e: dst=n} xb[src]                   (SpMM row-sum, F=128)
//   h1    = bf16(cj * relu((a1 @ W1) * ci + b1))     (MFMA GEMM, cj fused)
//   a2[n] = sum_{e: dst=n} h1[src]                   (SpMM row-sum, F=256)
//   gsum[g] += (a2 @ W2) * ci + b2   per node row    (MFMA GEMM, atomic epi)
//   out = (gsum/cnt) @ Wl + bl                       (tiny GEMM)
// ---------------------------------------------------------------------------

typedef __attribute__((ext_vector_type(8))) short short8v;
typedef __attribute__((ext_vector_type(4))) float f32x4;

static __device__ __forceinline__ unsigned short f2bf(float f) {
  unsigned u = __float_as_uint(f);
  u += 0x7FFFu + ((u >> 16) & 1u);   // RTNE
  return (unsigned short)(u >> 16);
}
static __device__ __forceinline__ float bf2f(unsigned short h) {
  return __uint_as_float(((unsigned)h) << 16);
}

__global__ void k_degrees(const int* __restrict__ src, const int* __restrict__ dst,
                          int* __restrict__ outdeg, int* __restrict__ indeg, int E) {
  int i = blockIdx.x * blockDim.x + threadIdx.x;
  if (i < E) {
    atomicAdd(&outdeg[src[i]], 1);
    atomicAdd(&indeg[dst[i]], 1);
  }
}

__global__ void k_norms_rows(const int* __restrict__ outdeg, const int* __restrict__ indeg,
                             float* __restrict__ cj, float* __restrict__ ci,
                             int* __restrict__ row_start, int* __restrict__ counter, int N) {
  int i = blockIdx.x * blockDim.x + threadIdx.x;
  int din = 0;
  if (i < N) {
    int dout = outdeg[i];
    din = indeg[i];
    cj[i] = rsqrtf((float)(dout > 1 ? dout : 1));
    ci[i] = rsqrtf((float)(din  > 1 ? din  : 1));
  }
  int lane = threadIdx.x & 63;
  int inc = din;
#pragma unroll
  for (int off = 1; off < 64; off <<= 1) {
    int o = __shfl_up(inc, off);
    if (lane >= off) inc += o;
  }
  int excl = inc - din;
  int wsum = __shfl(inc, 63);
  int base = 0;
  if (lane == 0) base = atomicAdd(counter, wsum);
  base = __shfl(base, 0);
  if (i < N) row_start[i] = base + excl;
}

__global__ void k_fill(const int* __restrict__ src, const int* __restrict__ dst,
                       const int* __restrict__ row_start, int* __restrict__ cursor,
                       int* __restrict__ csr_src, int E) {
  int i = blockIdx.x * blockDim.x + threadIdx.x;
  if (i < E) {
    int d = dst[i];
    int pos = row_start[d] + atomicAdd(&cursor[d], 1);
    csr_src[pos] = src[i];
  }
}

// f32 -> bf16 cast with per-row cj scale; 4 elements/thread, rows of 128.
__global__ void k_cast_scale(const float4* __restrict__ x, const float* __restrict__ cj,
                             unsigned short* __restrict__ o, int n4) {
  int i = blockIdx.x * blockDim.x + threadIdx.x;
  if (i < n4) {
    float c = cj[i >> 5];            // 32 float4 per 128-wide row
    float4 v = x[i];
    uint2 r;
    r.x = (unsigned)f2bf(c * v.x) | ((unsigned)f2bf(c * v.y) << 16);
    r.y = (unsigned)f2bf(c * v.z) | ((unsigned)f2bf(c * v.w) << 16);
    *(uint2*)(o + (size_t)i * 4) = r;
  }
}

// W[K][Nn] f32 -> BT[Nn][K] bf16 (transpose + cast; tiny).
__global__ void k_castT(const float* __restrict__ W, unsigned short* __restrict__ BT,
                        int K, int Nn) {
  int i = blockIdx.x * blockDim.x + threadIdx.x;
  if (i < K * Nn) {
    int k = i / Nn, nn = i - k * Nn;
    BT[(size_t)nn * K + k] = f2bf(W[i]);
  }
}

// Pure row-sum gather: one 64-thread block per destination node, unroll-4 ILP.
// VU = uints per lane per row (1 -> F=128, 2 -> F=256).
template <int VU>
__global__ void k_spmm(const unsigned* __restrict__ feat,
                       const int* __restrict__ row_start, const int* __restrict__ cnts,
                       const int* __restrict__ csr_src, unsigned* __restrict__ out, int N) {
  int n = blockIdx.x;
  if (n >= N) return;
  int beg = row_start[n];
  int cnt = cnts[n];
  int t = threadIdx.x;
  const int stride = VU * 64;
  float acc[2 * VU];
#pragma unroll
  for (int v = 0; v < 2 * VU; ++v) acc[v] = 0.f;

  int k = 0;
  for (; k + 4 <= cnt; k += 4) {
    int s0 = csr_src[beg + k + 0];
    int s1 = csr_src[beg + k + 1];
    int s2 = csr_src[beg + k + 2];
    int s3 = csr_src[beg + k + 3];
    if constexpr (VU == 2) {
      uint2 w0 = *(const uint2*)(feat + (size_t)s0 * stride + t * 2);
      uint2 w1 = *(const uint2*)(feat + (size_t)s1 * stride + t * 2);
      uint2 w2 = *(const uint2*)(feat + (size_t)s2 * stride + t * 2);
      uint2 w3 = *(const uint2*)(feat + (size_t)s3 * stride + t * 2);
      acc[0] += bf2f((unsigned short)(w0.x & 0xFFFF)) + bf2f((unsigned short)(w1.x & 0xFFFF))
              + bf2f((unsigned short)(w2.x & 0xFFFF)) + bf2f((unsigned short)(w3.x & 0xFFFF));
      acc[1] += bf2f((unsigned short)(w0.x >> 16)) + bf2f((unsigned short)(w1.x >> 16))
              + bf2f((unsigned short)(w2.x >> 16)) + bf2f((unsigned short)(w3.x >> 16));
      acc[2] += bf2f((unsigned short)(w0.y & 0xFFFF)) + bf2f((unsigned short)(w1.y & 0xFFFF))
              + bf2f((unsigned short)(w2.y & 0xFFFF)) + bf2f((unsigned short)(w3.y & 0xFFFF));
      acc[3] += bf2f((unsigned short)(w0.y >> 16)) + bf2f((unsigned short)(w1.y >> 16))
              + bf2f((unsigned short)(w2.y >> 16)) + bf2f((unsigned short)(w3.y >> 16));
    } else {
      unsigned w0 = feat[(size_t)s0 * stride + t];
      unsigned w1 = feat[(size_t)s1 * stride + t];
      unsigned w2 = feat[(size_t)s2 * stride + t];
      unsigned w3 = feat[(size_t)s3 * stride + t];
      acc[0] += bf2f((unsigned short)(w0 & 0xFFFF)) + bf2f((unsigned short)(w1 & 0xFFFF))
              + bf2f((unsigned short)(w2 & 0xFFFF)) + bf2f((unsigned short)(w3 & 0xFFFF));
      acc[1] += bf2f((unsigned short)(w0 >> 16)) + bf2f((unsigned short)(w1 >> 16))
              + bf2f((unsigned short)(w2 >> 16)) + bf2f((unsigned short)(w3 >> 16));
    }
  }
  for (; k < cnt; ++k) {
    int s = csr_src[beg + k];
    if constexpr (VU == 2) {
      uint2 w = *(const uint2*)(feat + (size_t)s * stride + t * 2);
      acc[0] += bf2f((unsigned short)(w.x & 0xFFFF));
      acc[1] += bf2f((unsigned short)(w.x >> 16));
      acc[2] += bf2f((unsigned short)(w.y & 0xFFFF));
      acc[3] += bf2f((unsigned short)(w.y >> 16));
    } else {
      unsigned w = feat[(size_t)s * stride + t];
      acc[0] += bf2f((unsigned short)(w & 0xFFFF));
      acc[1] += bf2f((unsigned short)(w >> 16));
    }
  }

  unsigned* o = out + (size_t)n * stride + t * VU;
  if constexpr (VU == 2) {
    uint2 r;
    r.x = (unsigned)f2bf(acc[0]) | ((unsigned)f2bf(acc[1]) << 16);
    r.y = (unsigned)f2bf(acc[2]) | ((unsigned)f2bf(acc[3]) << 16);
    *(uint2*)o = r;
  } else {
    *o = (unsigned)f2bf(acc[0]) | ((unsigned)f2bf(acc[1]) << 16);
  }
}

// MFMA GEMM: C[M,256] = A[M,K](bf16) @ B[K,256](bf16, given as BT[256][K]).
// Block: 256 thr = 4 waves; tile 128 rows x 64 cols; wave = 32 rows (2 subtiles).
// B panel staged in LDS pre-arranged in per-lane fragment order (conflict-free).
// EPI 0: h1[row,col] = bf16(cj[row] * relu(acc*ci[row] + bias[col]))
// EPI 1: atomicAdd(gsum[gid[row]*256+col], acc*ci[row] + bias[col])
template <int K, int EPI>
__global__ __launch_bounds__(256)
void k_gemm_mfma(const unsigned short* __restrict__ A, const unsigned short* __restrict__ BT,
                 const float* __restrict__ ci, const float* __restrict__ bias,
                 const float* __restrict__ cjv, const int* __restrict__ gids,
                 void* __restrict__ outp, int M) {
  constexpr int NF = (K / 32) * 4;          // fragments per 64-col panel
  __shared__ unsigned short Bs[NF * 64 * 8];
  const int tid = threadIdx.x;
  const int lane = tid & 63;
  const int wave = tid >> 6;
  const int col0 = blockIdx.y * 64;
  const int l15 = lane & 15;
  const int kA = (lane >> 4) * 8;

  // Stage B panel into LDS in fragment order: Bs[(f*64 + lane)*8 + j] with
  // f = (kc/32)*4 + ct  holding BT[col0 + ct*16 + (lane&15)][kc + (lane>>4)*8 + j].
  {
    constexpr int CH = NF * 64;             // 16B chunks
#pragma unroll
    for (int c = tid; c < CH; c += 256) {
      int f = c >> 6, l = c & 63;
      int ct = f & 3, kb = f >> 2;
      int col = col0 + ct * 16 + (l & 15);
      int ko = kb * 32 + (l >> 4) * 8;
      *(uint4*)&Bs[(size_t)c * 8] = *(const uint4*)(BT + (size_t)col * K + ko);
    }
  }
  __syncthreads();

  const int rowW = blockIdx.x * 128 + wave * 32;
  f32x4 acc0[4], acc1[4];
#pragma unroll
  for (int i = 0; i < 4; ++i) {
    acc0[i] = (f32x4){0.f, 0.f, 0.f, 0.f};
    acc1[i] = (f32x4){0.f, 0.f, 0.f, 0.f};
  }

  const unsigned short* aP0 = A + (size_t)(rowW + l15) * K + kA;
  const unsigned short* aP1 = aP0 + (size_t)16 * K;
  const unsigned short* bL = Bs + lane * 8;

#pragma unroll
  for (int kc = 0; kc < K; kc += 32) {
    short8v a0 = *(const short8v*)(aP0 + kc);
    short8v a1 = *(const short8v*)(aP1 + kc);
    const int fb = (kc >> 5) * 4;
#pragma unroll
    for (int ct = 0; ct < 4; ++ct) {
      short8v bv = *(const short8v*)(bL + (size_t)(fb + ct) * 512);
      acc0[ct] = __builtin_amdgcn_mfma_f32_16x16x32_bf16(a0, bv, acc0[ct], 0, 0, 0);
      acc1[ct] = __builtin_amdgcn_mfma_f32_16x16x32_bf16(a1, bv, acc1[ct], 0, 0, 0);
    }
  }

  const int rBase = rowW + (lane >> 4) * 4;
  if constexpr (EPI == 0) {
    unsigned short* out = (unsigned short*)outp;
#pragma unroll
    for (int half = 0; half < 2; ++half) {
      const f32x4* acc = half ? acc1 : acc0;
#pragma unroll
      for (int r = 0; r < 4; ++r) {
        int row = rBase + half * 16 + r;
        if (row < M) {
          float s = ci[row];
          float cjr = cjv[row];
#pragma unroll
          for (int ct = 0; ct < 4; ++ct) {
            int col = col0 + ct * 16 + l15;
            float v = fmaxf(acc[ct][r] * s + bias[col], 0.f) * cjr;
            out[(size_t)row * 256 + col] = f2bf(v);
          }
        }
      }
    }
  } else {
    float* gsum = (float*)outp;
#pragma unroll
    for (int half = 0; half < 2; ++half) {
      const f32x4* acc = half ? acc1 : acc0;
      int g[4];
      float cir[4];
#pragma unroll
      for (int r = 0; r < 4; ++r) {
        int row = rBase + half * 16 + r;
        bool ok = row < M;
        g[r] = ok ? gids[row] : -1;
        cir[r] = ok ? ci[row] : 0.f;
      }
#pragma unroll
      for (int ct = 0; ct < 4; ++ct) {
        int col = col0 + ct * 16 + l15;
        float bb = bias[col];
        float v0 = acc[ct][0] * cir[0] + bb;
        float v1 = acc[ct][1] * cir[1] + bb;
        float v2 = acc[ct][2] * cir[2] + bb;
        float v3 = acc[ct][3] * cir[3] + bb;
        if (g[0] == g[3] && g[0] >= 0) {   // gid sorted -> all 4 equal
          atomicAdd(&gsum[(size_t)g[0] * 256 + col], v0 + v1 + v2 + v3);
        } else {
          if (g[0] >= 0) atomicAdd(&gsum[(size_t)g[0] * 256 + col], v0);
          if (g[1] >= 0) atomicAdd(&gsum[(size_t)g[1] * 256 + col], v1);
          if (g[2] >= 0) atomicAdd(&gsum[(size_t)g[2] * 256 + col], v2);
          if (g[3] >= 0) atomicAdd(&gsum[(size_t)g[3] * 256 + col], v3);
        }
      }
    }
  }
}

__global__ void k_readout(const float* __restrict__ gsum, const int* __restrict__ gids,
                          const float* __restrict__ Wl, const float* __restrict__ bl,
                          float* __restrict__ out, int N, int da, int L) {
  int g = blockIdx.x;
  int lo = 0, hi = N;
  while (lo < hi) { int m = (lo + hi) >> 1; if (gids[m] < g) lo = m + 1; else hi = m; }
  int lo2 = lo, hi2 = N;
  while (lo2 < hi2) { int m = (lo2 + hi2) >> 1; if (gids[m] < g + 1) lo2 = m + 1; else hi2 = m; }
  int cnt = lo2 - lo;
  float inv = 1.0f / (float)(cnt > 1 ? cnt : 1);
  int l = threadIdx.x;
  if (l < L) {
    float acc = bl[l];
    for (int k = 0; k < da; ++k) acc += gsum[g * da + k] * inv * Wl[k * L + l];
    out[g * L + l] = acc;
  }
}

static inline size_t alignup(size_t v) { return (v + 255) & ~(size_t)255; }

extern "C" void kernel_launch(void* const* d_in, const int* in_sizes, int n_in,
                              void* d_out, int out_size, void* d_ws, size_t ws_size,
                              hipStream_t stream) {
  const float* x   = (const float*)d_in[0];
  const int*   src = (const int*)d_in[1];
  const int*   dst = (const int*)d_in[2];
  const int*   gid = (const int*)d_in[3];
  const float* W1  = (const float*)d_in[5];
  const float* b1  = (const float*)d_in[6];
  const float* W2  = (const float*)d_in[7];
  const float* b2  = (const float*)d_in[8];
  const float* Wl  = (const float*)d_in[9];
  const float* bl  = (const float*)d_in[10];
  float* out = (float*)d_out;

  const int N  = in_sizes[3];        // 50000
  const int E  = in_sizes[1];        // 800000
  const int da = in_sizes[8];        // 256
  const int L  = in_sizes[10];       // 50
  const int G  = out_size / L;       // 64
  const int RB = (N + 127) / 128;    // row blocks (128 rows)
  const int Npad = RB * 128;

  char* p = (char*)d_ws;
  int*   outdeg   = (int*)p;   p += alignup((size_t)N * 4);
  int*   indeg    = (int*)p;   p += alignup((size_t)N * 4);
  int*   cursor   = (int*)p;   p += alignup((size_t)N * 4);
  int*   counter  = (int*)p;   p += 256;
  float* gsum     = (float*)p; p += alignup((size_t)G * 256 * 4);
  size_t zero_bytes = (size_t)(p - (char*)d_ws);
  float* cj       = (float*)p; p += alignup((size_t)N * 4);
  float* ci       = (float*)p; p += alignup((size_t)N * 4);
  int*   row_start= (int*)p;   p += alignup((size_t)N * 4);
  int*   csr_src  = (int*)p;   p += alignup((size_t)E * 4);
  unsigned short* xb  = (unsigned short*)p; p += alignup((size_t)Npad * 128 * 2);
  unsigned short* a1  = (unsigned short*)p; p += alignup((size_t)Npad * 128 * 2);
  unsigned short* h1  = (unsigned short*)p; p += alignup((size_t)Npad * 256 * 2);
  unsigned short* a2  = (unsigned short*)p; p += alignup((size_t)Npad * 256 * 2);
  unsigned short* BT1 = (unsigned short*)p; p += alignup((size_t)256 * 128 * 2);
  unsigned short* BT2 = (unsigned short*)p; p += alignup((size_t)256 * 256 * 2);
  (void)ws_size; (void)n_in;

  hipMemsetAsync(d_ws, 0, zero_bytes, stream);

  k_degrees<<<(E + 255) / 256, 256, 0, stream>>>(src, dst, outdeg, indeg, E);
  k_norms_rows<<<(N + 255) / 256, 256, 0, stream>>>(outdeg, indeg, cj, ci, row_start, counter, N);
  k_fill<<<(E + 255) / 256, 256, 0, stream>>>(src, dst, row_start, cursor, csr_src, E);

  k_castT<<<(128 * 256 + 255) / 256, 256, 0, stream>>>(W1, BT1, 128, 256);
  k_castT<<<(256 * 256 + 255) / 256, 256, 0, stream>>>(W2, BT2, 256, 256);
  k_cast_scale<<<(N * 128 / 4 + 255) / 256, 256, 0, stream>>>((const float4*)x, cj, xb,
                                                              N * 128 / 4);

  k_spmm<1><<<N, 64, 0, stream>>>((const unsigned*)xb, row_start, indeg, csr_src,
                                  (unsigned*)a1, N);

  dim3 gg(RB, 4);
  k_gemm_mfma<128, 0><<<gg, 256, 0, stream>>>(a1, BT1, ci, b1, cj, nullptr, h1, N);

  k_spmm<2><<<N, 64, 0, stream>>>((const unsigned*)h1, row_start, indeg, csr_src,
                                  (unsigned*)a2, N);

  k_gemm_mfma<256, 1><<<gg, 256, 0, stream>>>(a2, BT2, ci, b2, nullptr, gid, gsum, N);

  k_readout<<<G, 64, 0, stream>>>(gsum, gid, Wl, bl, out, N, da, L);
}

// Round 4
// 291.519 us; speedup vs baseline: 2.9603x; 1.3623x over previous
//
#include <hip/hip_runtime.h>
#include <cstdint>

// ---------------------------------------------------------------------------
// GCN graph classification on MI355X (gfx950), v4.
//   deg -> cj=rsqrt(outdeg), ci=rsqrt(indeg); CSR by dst built on device
//   xb  = bf16(cj * x)
//   a1[n] = sum_{e: dst=n} xb[src]                   (SpMM row-sum, F=128)
//   h1    = bf16(cj * relu((a1 @ W1) * ci + b1))     (MFMA GEMM, A-preload)
//   t[g]  = sum_e ci[dst_e] * h1[src_e]  (gid[dst])  (edge pool, f32 acc)
//   out   = ((t + cnt*b2)/cnt) @ W2 ... @ Wl + bl    (tiny fused readout)
// ---------------------------------------------------------------------------

typedef __attribute__((ext_vector_type(8))) short short8v;
typedef __attribute__((ext_vector_type(4))) float f32x4;

static __device__ __forceinline__ unsigned short f2bf(float f) {
  unsigned u = __float_as_uint(f);
  u += 0x7FFFu + ((u >> 16) & 1u);   // RTNE
  return (unsigned short)(u >> 16);
}
static __device__ __forceinline__ float bf2f(unsigned short h) {
  return __uint_as_float(((unsigned)h) << 16);
}

__global__ void k_degrees(const int* __restrict__ src, const int* __restrict__ dst,
                          int* __restrict__ outdeg, int* __restrict__ indeg, int E) {
  int i = blockIdx.x * blockDim.x + threadIdx.x;
  if (i < E) {
    atomicAdd(&outdeg[src[i]], 1);
    atomicAdd(&indeg[dst[i]], 1);
  }
}

__global__ void k_norms_rows(const int* __restrict__ outdeg, const int* __restrict__ indeg,
                             float* __restrict__ cj, float* __restrict__ ci,
                             int* __restrict__ row_start, int* __restrict__ counter, int N) {
  int i = blockIdx.x * blockDim.x + threadIdx.x;
  int din = 0;
  if (i < N) {
    int dout = outdeg[i];
    din = indeg[i];
    cj[i] = rsqrtf((float)(dout > 1 ? dout : 1));
    ci[i] = rsqrtf((float)(din  > 1 ? din  : 1));
  }
  int lane = threadIdx.x & 63;
  int inc = din;
#pragma unroll
  for (int off = 1; off < 64; off <<= 1) {
    int o = __shfl_up(inc, off);
    if (lane >= off) inc += o;
  }
  int excl = inc - din;
  int wsum = __shfl(inc, 63);
  int base = 0;
  if (lane == 0) base = atomicAdd(counter, wsum);
  base = __shfl(base, 0);
  if (i < N) row_start[i] = base + excl;
}

__global__ void k_fill(const int* __restrict__ src, const int* __restrict__ dst,
                       const int* __restrict__ row_start, int* __restrict__ cursor,
                       int* __restrict__ csr_src, int E) {
  int i = blockIdx.x * blockDim.x + threadIdx.x;
  if (i < E) {
    int d = dst[i];
    int pos = row_start[d] + atomicAdd(&cursor[d], 1);
    csr_src[pos] = src[i];
  }
}

// f32 -> bf16 cast with per-row cj scale; 4 elements/thread, rows of 128.
__global__ void k_cast_scale(const float4* __restrict__ x, const float* __restrict__ cj,
                             unsigned short* __restrict__ o, int n4) {
  int i = blockIdx.x * blockDim.x + threadIdx.x;
  if (i < n4) {
    float c = cj[i >> 5];            // 32 float4 per 128-wide row
    float4 v = x[i];
    uint2 r;
    r.x = (unsigned)f2bf(c * v.x) | ((unsigned)f2bf(c * v.y) << 16);
    r.y = (unsigned)f2bf(c * v.z) | ((unsigned)f2bf(c * v.w) << 16);
    *(uint2*)(o + (size_t)i * 4) = r;
  }
}

// W[K][Nn] f32 -> BT[Nn][K] bf16 (transpose + cast; tiny).
__global__ void k_castT(const float* __restrict__ W, unsigned short* __restrict__ BT,
                        int K, int Nn) {
  int i = blockIdx.x * blockDim.x + threadIdx.x;
  if (i < K * Nn) {
    int k = i / Nn, nn = i - k * Nn;
    BT[(size_t)nn * K + k] = f2bf(W[i]);
  }
}

// Pure row-sum gather: one 64-thread block per destination node, unroll-4 ILP.
__global__ void k_spmm(const unsigned* __restrict__ feat,
                       const int* __restrict__ row_start, const int* __restrict__ cnts,
                       const int* __restrict__ csr_src, unsigned* __restrict__ out, int N) {
  int n = blockIdx.x;
  if (n >= N) return;
  int beg = row_start[n];
  int cnt = cnts[n];
  int t = threadIdx.x;
  float acc0 = 0.f, acc1 = 0.f;

  int k = 0;
  for (; k + 4 <= cnt; k += 4) {
    int s0 = csr_src[beg + k + 0];
    int s1 = csr_src[beg + k + 1];
    int s2 = csr_src[beg + k + 2];
    int s3 = csr_src[beg + k + 3];
    unsigned w0 = feat[(size_t)s0 * 64 + t];
    unsigned w1 = feat[(size_t)s1 * 64 + t];
    unsigned w2 = feat[(size_t)s2 * 64 + t];
    unsigned w3 = feat[(size_t)s3 * 64 + t];
    acc0 += bf2f((unsigned short)(w0 & 0xFFFF)) + bf2f((unsigned short)(w1 & 0xFFFF))
          + bf2f((unsigned short)(w2 & 0xFFFF)) + bf2f((unsigned short)(w3 & 0xFFFF));
    acc1 += bf2f((unsigned short)(w0 >> 16)) + bf2f((unsigned short)(w1 >> 16))
          + bf2f((unsigned short)(w2 >> 16)) + bf2f((unsigned short)(w3 >> 16));
  }
  for (; k < cnt; ++k) {
    int s = csr_src[beg + k];
    unsigned w = feat[(size_t)s * 64 + t];
    acc0 += bf2f((unsigned short)(w & 0xFFFF));
    acc1 += bf2f((unsigned short)(w >> 16));
  }
  out[(size_t)n * 64 + t] = (unsigned)f2bf(acc0) | ((unsigned)f2bf(acc1) << 16);
}

// MFMA GEMM1: h1[M,256] = f(A[M,128] @ W1). Block: 4 waves, 128 rows x 256 cols.
// B fully staged in LDS (fragment order, 64KB); A frags preloaded to registers.
__global__ __launch_bounds__(256, 2)
void k_gemm_mfma(const unsigned short* __restrict__ A, const unsigned short* __restrict__ BT,
                 const float* __restrict__ ci, const float* __restrict__ bias,
                 const float* __restrict__ cjv, unsigned short* __restrict__ out, int M) {
  constexpr int K = 128;
  __shared__ unsigned short Bs[64 * 64 * 8];   // 64 frags x 64 lanes x 8 bf16 = 64KB
  const int tid = threadIdx.x;
  const int lane = tid & 63;
  const int wave = tid >> 6;
  const int l15 = lane & 15;
  const int kA = (lane >> 4) * 8;

  // Stage B: frag f = kb*16+ct holds BT[ct*16+(l&15)][kb*32+(l>>4)*8 + j]
#pragma unroll
  for (int it = 0; it < 16; ++it) {
    int c = it * 256 + tid;
    int f = c >> 6, l = c & 63;
    int ct = f & 15, kb = f >> 4;
    int col = ct * 16 + (l & 15);
    int ko = kb * 32 + (l >> 4) * 8;
    *(uint4*)&Bs[(size_t)c * 8] = *(const uint4*)(BT + (size_t)col * K + ko);
  }
  __syncthreads();

  const int rowW = blockIdx.x * 128 + wave * 32;
  const unsigned short* aP0 = A + (size_t)(rowW + l15) * K + kA;
  const unsigned short* aP1 = aP0 + (size_t)16 * K;

  // Preload all A fragments (8 x b128 = 64 VGPR), issued back-to-back.
  short8v a0[4], a1[4];
#pragma unroll
  for (int kb = 0; kb < 4; ++kb) {
    a0[kb] = *(const short8v*)(aP0 + kb * 32);
    a1[kb] = *(const short8v*)(aP1 + kb * 32);
  }

  f32x4 acc0[16], acc1[16];
#pragma unroll
  for (int i = 0; i < 16; ++i) {
    acc0[i] = (f32x4){0.f, 0.f, 0.f, 0.f};
    acc1[i] = (f32x4){0.f, 0.f, 0.f, 0.f};
  }

  const unsigned short* bL = Bs + lane * 8;
#pragma unroll
  for (int kb = 0; kb < 4; ++kb) {
#pragma unroll
    for (int ct = 0; ct < 16; ++ct) {
      short8v bv = *(const short8v*)(bL + (size_t)(kb * 16 + ct) * 512);
      acc0[ct] = __builtin_amdgcn_mfma_f32_16x16x32_bf16(a0[kb], bv, acc0[ct], 0, 0, 0);
      acc1[ct] = __builtin_amdgcn_mfma_f32_16x16x32_bf16(a1[kb], bv, acc1[ct], 0, 0, 0);
    }
  }

  const int rBase = rowW + (lane >> 4) * 4;
#pragma unroll
  for (int half = 0; half < 2; ++half) {
    const f32x4* acc = half ? acc1 : acc0;
#pragma unroll
    for (int r = 0; r < 4; ++r) {
      int row = rBase + half * 16 + r;
      if (row < M) {
        float s = ci[row];
        float cjr = cjv[row];
#pragma unroll
        for (int ct = 0; ct < 16; ++ct) {
          int col = ct * 16 + l15;
          float v = fmaxf(acc[ct][r] * s + bias[col], 0.f) * cjr;
          out[(size_t)row * 256 + col] = f2bf(v);
        }
      }
    }
  }
}

// Edge pool: t[g] = sum_e ci[dst_e]*h1[src_e]; waves own contiguous node ranges
// (gid sorted -> flush registers on graph boundary only).
template <int CH>
__global__ void k_pool2(const unsigned* __restrict__ h1, const float* __restrict__ ci,
                        const int* __restrict__ row_start, const int* __restrict__ cnts,
                        const int* __restrict__ csr_src, const int* __restrict__ gid,
                        float* __restrict__ gsum, int N) {
  int wave = blockIdx.x * (blockDim.x >> 6) + (threadIdx.x >> 6);
  int lane = threadIdx.x & 63;
  int n0 = wave * CH;
  if (n0 >= N) return;
  int n1 = n0 + CH; if (n1 > N) n1 = N;

  float acc[4] = {0.f, 0.f, 0.f, 0.f};
  int curg = gid[n0];
  for (int n = n0; n < n1; ++n) {
    int g = gid[n];
    if (g != curg) {
      float* dp = gsum + (size_t)curg * 256 + lane * 4;
      if (acc[0] != 0.f || acc[1] != 0.f || acc[2] != 0.f || acc[3] != 0.f) {
        atomicAdd(dp + 0, acc[0]); atomicAdd(dp + 1, acc[1]);
        atomicAdd(dp + 2, acc[2]); atomicAdd(dp + 3, acc[3]);
      }
      acc[0] = acc[1] = acc[2] = acc[3] = 0.f;
      curg = g;
    }
    float c = ci[n];
    int beg = row_start[n];
    int cnt = cnts[n];
    int k = 0;
    for (; k + 4 <= cnt; k += 4) {
      int s0 = csr_src[beg + k + 0];
      int s1 = csr_src[beg + k + 1];
      int s2 = csr_src[beg + k + 2];
      int s3 = csr_src[beg + k + 3];
      uint2 w0 = *(const uint2*)(h1 + (size_t)s0 * 128 + lane * 2);
      uint2 w1 = *(const uint2*)(h1 + (size_t)s1 * 128 + lane * 2);
      uint2 w2 = *(const uint2*)(h1 + (size_t)s2 * 128 + lane * 2);
      uint2 w3 = *(const uint2*)(h1 + (size_t)s3 * 128 + lane * 2);
      acc[0] += c * (bf2f((unsigned short)(w0.x & 0xFFFF)) + bf2f((unsigned short)(w1.x & 0xFFFF))
                   + bf2f((unsigned short)(w2.x & 0xFFFF)) + bf2f((unsigned short)(w3.x & 0xFFFF)));
      acc[1] += c * (bf2f((unsigned short)(w0.x >> 16)) + bf2f((unsigned short)(w1.x >> 16))
                   + bf2f((unsigned short)(w2.x >> 16)) + bf2f((unsigned short)(w3.x >> 16)));
      acc[2] += c * (bf2f((unsigned short)(w0.y & 0xFFFF)) + bf2f((unsigned short)(w1.y & 0xFFFF))
                   + bf2f((unsigned short)(w2.y & 0xFFFF)) + bf2f((unsigned short)(w3.y & 0xFFFF)));
      acc[3] += c * (bf2f((unsigned short)(w0.y >> 16)) + bf2f((unsigned short)(w1.y >> 16))
                   + bf2f((unsigned short)(w2.y >> 16)) + bf2f((unsigned short)(w3.y >> 16)));
    }
    for (; k < cnt; ++k) {
      int s = csr_src[beg + k];
      uint2 w = *(const uint2*)(h1 + (size_t)s * 128 + lane * 2);
      acc[0] += c * bf2f((unsigned short)(w.x & 0xFFFF));
      acc[1] += c * bf2f((unsigned short)(w.x >> 16));
      acc[2] += c * bf2f((unsigned short)(w.y & 0xFFFF));
      acc[3] += c * bf2f((unsigned short)(w.y >> 16));
    }
  }
  float* dp = gsum + (size_t)curg * 256 + lane * 4;
  atomicAdd(dp + 0, acc[0]); atomicAdd(dp + 1, acc[1]);
  atomicAdd(dp + 2, acc[2]); atomicAdd(dp + 3, acc[3]);
}

// out[g] = ((t[g] @ W2 + cnt*b2)/max(cnt,1)) @ Wl + bl
__global__ __launch_bounds__(256)
void k_final(const float* __restrict__ gsum, const int* __restrict__ gids,
             const float* __restrict__ W2, const float* __restrict__ b2,
             const float* __restrict__ Wl, const float* __restrict__ bl,
             float* __restrict__ out, int N, int L) {
  int g = blockIdx.x;
  __shared__ float ts[256];
  __shared__ float hg[256];
  int lo = 0, hi = N;
  while (lo < hi) { int m = (lo + hi) >> 1; if (gids[m] < g) lo = m + 1; else hi = m; }
  int lo2 = lo, hi2 = N;
  while (lo2 < hi2) { int m = (lo2 + hi2) >> 1; if (gids[m] < g + 1) lo2 = m + 1; else hi2 = m; }
  int cnt = lo2 - lo;
  float inv = 1.0f / (float)(cnt > 1 ? cnt : 1);
  int c = threadIdx.x;
  ts[c] = gsum[(size_t)g * 256 + c];
  __syncthreads();
  float acc = (float)cnt * b2[c];
  for (int k = 0; k < 256; ++k) acc += ts[k] * W2[(size_t)k * 256 + c];
  hg[c] = acc * inv;
  __syncthreads();
  if (c < L) {
    float o = bl[c];
    for (int k = 0; k < 256; ++k) o += hg[k] * Wl[(size_t)k * L + c];
    out[(size_t)g * L + c] = o;
  }
}

static inline size_t alignup(size_t v) { return (v + 255) & ~(size_t)255; }

extern "C" void kernel_launch(void* const* d_in, const int* in_sizes, int n_in,
                              void* d_out, int out_size, void* d_ws, size_t ws_size,
                              hipStream_t stream) {
  const float* x   = (const float*)d_in[0];
  const int*   src = (const int*)d_in[1];
  const int*   dst = (const int*)d_in[2];
  const int*   gid = (const int*)d_in[3];
  const float* W1  = (const float*)d_in[5];
  const float* b1  = (const float*)d_in[6];
  const float* W2  = (const float*)d_in[7];
  const float* b2  = (const float*)d_in[8];
  const float* Wl  = (const float*)d_in[9];
  const float* bl  = (const float*)d_in[10];
  float* out = (float*)d_out;

  const int N  = in_sizes[3];        // 50000
  const int E  = in_sizes[1];        // 800000
  const int L  = in_sizes[10];       // 50
  const int G  = out_size / L;       // 64
  const int RB = (N + 127) / 128;    // GEMM row blocks
  const int Npad = RB * 128;

  char* p = (char*)d_ws;
  int*   outdeg   = (int*)p;   p += alignup((size_t)N * 4);
  int*   indeg    = (int*)p;   p += alignup((size_t)N * 4);
  int*   cursor   = (int*)p;   p += alignup((size_t)N * 4);
  int*   counter  = (int*)p;   p += 256;
  float* gsum     = (float*)p; p += alignup((size_t)G * 256 * 4);
  size_t zero_bytes = (size_t)(p - (char*)d_ws);
  float* cj       = (float*)p; p += alignup((size_t)N * 4);
  float* ci       = (float*)p; p += alignup((size_t)N * 4);
  int*   row_start= (int*)p;   p += alignup((size_t)N * 4);
  int*   csr_src  = (int*)p;   p += alignup((size_t)E * 4);
  unsigned short* xb  = (unsigned short*)p; p += alignup((size_t)Npad * 128 * 2);
  unsigned short* a1  = (unsigned short*)p; p += alignup((size_t)Npad * 128 * 2);
  unsigned short* h1  = (unsigned short*)p; p += alignup((size_t)Npad * 256 * 2);
  unsigned short* BT1 = (unsigned short*)p; p += alignup((size_t)256 * 128 * 2);
  (void)ws_size; (void)n_in;

  hipMemsetAsync(d_ws, 0, zero_bytes, stream);

  k_degrees<<<(E + 255) / 256, 256, 0, stream>>>(src, dst, outdeg, indeg, E);
  k_norms_rows<<<(N + 255) / 256, 256, 0, stream>>>(outdeg, indeg, cj, ci, row_start, counter, N);
  k_fill<<<(E + 255) / 256, 256, 0, stream>>>(src, dst, row_start, cursor, csr_src, E);

  k_castT<<<(128 * 256 + 255) / 256, 256, 0, stream>>>(W1, BT1, 128, 256);
  k_cast_scale<<<(N * 128 / 4 + 255) / 256, 256, 0, stream>>>((const float4*)x, cj, xb,
                                                              N * 128 / 4);

  k_spmm<<<N, 64, 0, stream>>>((const unsigned*)xb, row_start, indeg, csr_src,
                               (unsigned*)a1, N);

  k_gemm_mfma<<<RB, 256, 0, stream>>>(a1, BT1, ci, b1, cj, h1, N);

  constexpr int CH = 16;             // nodes per wave
  int pool_waves = (N + CH - 1) / CH;
  int pool_blocks = (pool_waves + 3) / 4;
  k_pool2<CH><<<pool_blocks, 256, 0, stream>>>((const unsigned*)h1, ci, row_start, indeg,
                                               csr_src, gid, gsum, N);

  k_final<<<G, 256, 0, stream>>>(gsum, gid, W2, b2, Wl, bl, out, N, L);
}